// Round 19
// baseline (484.698 us; speedup 1.0000x reference)
//
#include <hip/hip_runtime.h>
#include <hip/hip_bf16.h>
#include <math.h>

#define B_ 4
#define R_ 256
#define P_ 64
#define DP_ 384
#define DR_ 512
#define N_ 48
#define RK_ 24
#define MROWS (B_*R_*P_)   /* 65536 */
#define REGS  (B_*R_)      /* 1024  */

typedef unsigned short ushort_t;
typedef __attribute__((ext_vector_type(8))) short bf16x8;
typedef __attribute__((ext_vector_type(4))) float f32x4;

#define GLOAD16(g, l) __builtin_amdgcn_global_load_lds( \
    (const __attribute__((address_space(1))) unsigned int*)(g), \
    (__attribute__((address_space(3))) unsigned int*)(l), 16, 0, 0)

// bf16 weight blob segment offsets (elements) — [k][n] layout (coalesced)
#define OFF_PW1  0
#define OFF_PW2  196608
#define OFF_INPW 458752
#define OFF_XPW  983040
#define OFF_DTW  1044480
#define NW_TOT   1056768

__device__ __forceinline__ float us2f(unsigned short u){
  union { unsigned int i; float f; } x; x.i = ((unsigned int)u) << 16; return x.f;
}
__device__ __forceinline__ unsigned short f2us(float f){
  __hip_bfloat16 h = __float2bfloat16(f);
  return *reinterpret_cast<unsigned short*>(&h);
}
// fast gelu: sigmoid approximation x*sigmoid(1.702x) (|err| < 0.02 abs)
__device__ __forceinline__ float gelu_f(float x){
  return x / (1.0f + __expf(-1.702f * x));
}
__device__ __forceinline__ float wred_sum(float v){
#pragma unroll
  for (int m = 1; m < 64; m <<= 1) v += __shfl_xor(v, m, 64);
  return v;
}
// 4 simultaneous block-wide sums (512-thread blocks); s >= 40 floats
__device__ __forceinline__ void block_sum4(float v[4], float* s){
  int lane = threadIdx.x & 63, wid = threadIdx.x >> 6;
#pragma unroll
  for (int i = 0; i < 4; ++i){
    float x = v[i];
#pragma unroll
    for (int m = 1; m < 64; m <<= 1) x += __shfl_xor(x, m, 64);
    if (lane == 0) s[wid * 4 + i] = x;
  }
  __syncthreads();
  if (threadIdx.x < 4){
    float t = 0.f;
    for (int t2 = 0; t2 < 8; ++t2) t += s[t2 * 4 + threadIdx.x];
    s[32 + threadIdx.x] = t;
  }
  __syncthreads();
#pragma unroll
  for (int i = 0; i < 4; ++i) v[i] = s[32 + i];
  __syncthreads();
}
// 2 simultaneous block-wide sums (512-thread blocks); s >= 18 floats
__device__ __forceinline__ void block_sum2(float& a, float& b, float* s){
  int lane = threadIdx.x & 63, wid = threadIdx.x >> 6;
  float x = a, y = b;
#pragma unroll
  for (int m = 1; m < 64; m <<= 1){ x += __shfl_xor(x, m, 64); y += __shfl_xor(y, m, 64); }
  if (lane == 0){ s[wid * 2] = x; s[wid * 2 + 1] = y; }
  __syncthreads();
  if (threadIdx.x < 2){
    float t = 0.f;
    for (int j = 0; j < 8; ++j) t += s[j * 2 + threadIdx.x];
    s[16 + threadIdx.x] = t;
  }
  __syncthreads();
  a = s[16]; b = s[17];
  __syncthreads();
}

// ---------------- C0: weight prep, parallel. 8 blocks x 512 ----------------
__global__ __launch_bounds__(512) void k_prep(
    const float* __restrict__ gw1, const float* __restrict__ glnw,
    const float* __restrict__ glnb, const float* __restrict__ gb1,
    ushort_t* __restrict__ W1pT, float* __restrict__ s1,
    float* __restrict__ b1p, float* __restrict__ accum){
  __shared__ float pss[8][64], psb[8][64];
  int tid = threadIdx.x, seg = tid >> 6, nl = tid & 63;
  int n = blockIdx.x * 64 + nl;
  if (blockIdx.x == 0 && tid < 4) accum[tid] = 0.f;
  float s = 0.f, sb = 0.f;
  int k0 = seg * 48;
  for (int i = 0; i < 48; ++i){
    int k = k0 + i;
    float w1 = gw1[k * DR_ + n];
    float v = glnw[k] * w1;
    unsigned short vr = f2us(v);
    s  += us2f(vr);
    sb += glnb[k] * w1;
    W1pT[(size_t)n * DP_ + k] = vr;
  }
  pss[seg][nl] = s; psb[seg][nl] = sb;
  __syncthreads();
  if (tid < 64){
    float ts = 0.f, tb = 0.f;
    for (int j = 0; j < 8; ++j){ ts += pss[j][tid]; tb += psb[j][tid]; }
    s1[blockIdx.x * 64 + tid] = ts;
    b1p[blockIdx.x * 64 + tid] = gb1[blockIdx.x * 64 + tid] + tb;
  }
}

// ---------------- C1: cast region-chain weights f32 -> bf16 blob -----------
__global__ __launch_bounds__(512) void k_cast(
    const float* __restrict__ pw1, const float* __restrict__ pw2,
    const float* __restrict__ inpw, const float* __restrict__ xpw,
    const float* __restrict__ dtw, ushort_t* __restrict__ dst){
  int i = (blockIdx.x * 512 + threadIdx.x) * 4;
  if (i >= NW_TOT) return;
  const float* s; int off;
  if (i < OFF_PW2){ s = pw1; off = OFF_PW1; }
  else if (i < OFF_INPW){ s = pw2; off = OFF_PW2; }
  else if (i < OFF_XPW){ s = inpw; off = OFF_INPW; }
  else if (i < OFF_DTW){ s = xpw; off = OFF_XPW; }
  else { s = dtw; off = OFF_DTW; }
  float4 v = *(const float4*)(s + (i - off));
  ushort_t* d = dst + i;
  d[0] = f2us(v.x); d[1] = f2us(v.y); d[2] = f2us(v.z); d[3] = f2us(v.w);
}

// ---------------- S0: xb = bf16(pt + lp) + LN stats. 8 rows/block ----------
__global__ __launch_bounds__(512) void k_xform(
    const float* __restrict__ pt, const float* __restrict__ lp,
    ushort_t* __restrict__ xb, float* __restrict__ mu, float* __restrict__ rsg){
  int tid = threadIdx.x, w = tid >> 6, lane = tid & 63;
  size_t r = (size_t)blockIdx.x * 8 + w;
  int p = (int)(r & (P_ - 1));
  const float* xr = pt + r * DP_ + lane * 6;
  const float* lr = lp + (size_t)p * DP_ + lane * 6;
  float x[6];
  float s = 0.f, ss = 0.f;
#pragma unroll
  for (int i = 0; i < 6; i += 2){
    float2 a = *(const float2*)(xr + i);
    float2 b = *(const float2*)(lr + i);
    x[i] = a.x + b.x; x[i + 1] = a.y + b.y;
  }
#pragma unroll
  for (int i = 0; i < 6; ++i){ s += x[i]; ss += x[i] * x[i]; }
  s = wred_sum(s); ss = wred_sum(ss);
  if (lane == 0){
    float m = s * (1.f / DP_);
    float var = ss * (1.f / DP_) - m * m;
    mu[r] = m;
    rsg[r] = rsqrtf(var + 1e-5f);
  }
  ushort_t* xw = xb + r * DP_ + lane * 6;
#pragma unroll
  for (int i = 0; i < 6; i += 2){
    ushort2 u2; u2.x = f2us(x[i]); u2.y = f2us(x[i + 1]);
    *(ushort2*)(xw + i) = u2;
  }
}

// ---- P2 fused: gate GEMM (BM=128, 16 waves) + folded LN + gelu + logit
//      (contention-free LDS-partial reduce) + softmax + attention pooling.
__global__ __launch_bounds__(1024, 4) void k_gate_pool(
    const ushort_t* __restrict__ xb,   // (65536 x 384) bf16
    const ushort_t* __restrict__ BT,   // W1pT (512 x 384) bf16
    const float* __restrict__ mu, const float* __restrict__ rsg,
    const float* __restrict__ s1, const float* __restrict__ b1p,
    const float* __restrict__ w2, const int* __restrict__ pmask,
    float* __restrict__ pooled){
  __shared__ __align__(16) ushort_t Abuf[2][128 * 64];   // 32 KB; pool scratch later
  __shared__ float wpart[16][128];                       // 8 KB
  __shared__ float logit_lds[128];
  __shared__ float smu[128], srs[128];
  __shared__ float attn2[2][64];
  int tid = threadIdx.x;
  int lane = tid & 63, w = tid >> 6;        // w: 0..15
  int t = lane & 15, g = lane >> 4;
  long r0 = (long)blockIdx.x * 128;
  if (tid < 128){
    smu[tid] = mu[r0 + tid];
    srs[tid] = rsg[r0 + tid];
  }

  f32x4 acc[8][2];
#pragma unroll
  for (int m = 0; m < 8; ++m)
#pragma unroll
    for (int n = 0; n < 2; ++n) acc[m][n] = (f32x4){0.f, 0.f, 0.f, 0.f};

  // staging: wave w stages rows w*8..w*8+7 (whole 128x64 tile in 1 instr)
  int ro = lane >> 3, c = lane & 7;
  int srow = (w << 3) + ro;
  const ushort_t* asrc = xb + (size_t)(r0 + srow) * DP_ + ((c ^ (srow & 7)) << 3);

  GLOAD16(asrc, Abuf[0] + (w << 9));
  __syncthreads();                    // buf0 ready

  for (int kt = 0; kt < 6; ++kt){
    int cb = kt & 1;
    if (kt < 5) GLOAD16(asrc + (kt + 1) * 64, Abuf[cb ^ 1] + (w << 9));
    // B fragments: wave owns cols w*32 + n*16 + t
    bf16x8 bfr[2][2];
#pragma unroll
    for (int kk = 0; kk < 2; ++kk)
#pragma unroll
      for (int n = 0; n < 2; ++n){
        int col = w * 32 + n * 16 + t;
        bfr[kk][n] = *(const bf16x8*)(BT + (size_t)col * DP_ + kt * 64 + (kk * 4 + g) * 8);
      }
#pragma unroll
    for (int kk = 0; kk < 2; ++kk){
      int ch = kk * 4 + g;
#pragma unroll
      for (int m = 0; m < 8; ++m){
        int row = m * 16 + t;
        bf16x8 af = *(const bf16x8*)(Abuf[cb] + row * 64 + ((ch ^ (row & 7)) << 3));
#pragma unroll
        for (int n = 0; n < 2; ++n)
          acc[m][n] = __builtin_amdgcn_mfma_f32_16x16x32_bf16(af, bfr[kk][n], acc[m][n], 0, 0, 0);
      }
    }
    __syncthreads();                  // next buf staged; current reads done
  }

  // epilogue: folded LN + gelu + per-wave partials (no atomics).
  // shuffles at width 16 (masks 1..8 stay in a row -> DPP, no DS ops)
  float w2c[2], s1c[2], b1c[2];
#pragma unroll
  for (int n = 0; n < 2; ++n){
    int col = w * 32 + n * 16 + t;
    w2c[n] = w2[col]; s1c[n] = s1[col]; b1c[n] = b1p[col];
  }
#pragma unroll
  for (int m = 0; m < 8; ++m){
#pragma unroll
    for (int j = 0; j < 4; ++j){
      int rl = m * 16 + g * 4 + j;
      float mur = smu[rl], rs = srs[rl];
      float part = 0.f;
#pragma unroll
      for (int n = 0; n < 2; ++n){
        float gp = rs * acc[m][n][j] - mur * rs * s1c[n] + b1c[n];
        part += gelu_f(gp) * w2c[n];
      }
#pragma unroll
      for (int msk = 1; msk < 16; msk <<= 1) part += __shfl_xor(part, msk, 16);
      if (t == 0) wpart[w][rl] = part;
    }
  }
  __syncthreads();
  if (tid < 128){
    float s = 0.f;
#pragma unroll
    for (int wi = 0; wi < 16; ++wi) s += wpart[wi][tid];
    logit_lds[tid] = s;               // gate_b2 cancels in softmax
  }
  __syncthreads();

  // masked softmax for each of the 2 regions (one full wave per half)
  int half = tid >> 9, lt = tid & 511;
  long rr0 = r0 + half * 64;
  if (lt < 64){
    int mk = pmask[rr0 + lt];
    float lv = logit_lds[half * 64 + lt];
    float lm = mk ? lv : -3.4e38f;
    float M = lm;
#pragma unroll
    for (int m2 = 1; m2 < 64; m2 <<= 1) M = fmaxf(M, __shfl_xor(M, m2, 64));
    float e = mk ? __expf(lv - M) : 0.f;
    float S = e;
#pragma unroll
    for (int m2 = 1; m2 < 64; m2 <<= 1) S += __shfl_xor(S, m2, 64);
    float a = (S > 0.f) ? e / S : 0.f;
    float S2 = a;
#pragma unroll
    for (int m2 = 1; m2 < 64; m2 <<= 1) S2 += __shfl_xor(S2, m2, 64);
    attn2[half][lt] = a / fmaxf(S2, 1e-6f);
  }
  __syncthreads();

  // attention pooling (xb L2/L3-hot); Abuf reused as f32 scratch [2][8][384]
  float* pbuf = (float*)Abuf;
  if (lt < 384){
    int pg = lt / 48, cc = lt % 48;
    float a8[8] = {0,0,0,0,0,0,0,0};
#pragma unroll
    for (int i = 0; i < 8; ++i){
      int p = pg + i * 8;
      bf16x8 v = *(const bf16x8*)(xb + (size_t)(rr0 + p) * DP_ + cc * 8);
      float ap = attn2[half][p];
#pragma unroll
      for (int j = 0; j < 8; ++j) a8[j] = fmaf(ap, us2f((unsigned short)v[j]), a8[j]);
    }
#pragma unroll
    for (int j = 0; j < 8; ++j) pbuf[(half * 8 + pg) * DP_ + cc * 8 + j] = a8[j];
  }
  __syncthreads();
  if (lt < 384){
    float s = 0.f;
#pragma unroll
    for (int g2 = 0; g2 < 8; ++g2) s += pbuf[(half * 8 + g2) * DP_ + lt];
    pooled[(long)(2 * blockIdx.x + half) * DP_ + lt] = s;
  }
}

// ---- R1+R3+R4 fused: region MLP -> in_proj -> x_proj. 2 rows/block,
//      512 blocks. Coalesced [k][n] weights; split acc chains; 8 waves/EU.
__global__ __launch_bounds__(512, 8) void k_region(
    const float* __restrict__ pooled,
    const float* __restrict__ ln1w, const float* __restrict__ ln1b,
    const ushort_t* __restrict__ wblob, const float* __restrict__ pb1,
    const float* __restrict__ pb2,
    const float* __restrict__ ln2w, const float* __restrict__ ln2b,
    const float* __restrict__ dtb,
    float* __restrict__ region, float* __restrict__ uT, float* __restrict__ zT,
    float* __restrict__ deltaT, float* __restrict__ BmT, float* __restrict__ CmT){
  const ushort_t* pw1b  = wblob + OFF_PW1;
  const ushort_t* pw2b  = wblob + OFF_PW2;
  const ushort_t* inpwb = wblob + OFF_INPW;
  const ushort_t* xpwb  = wblob + OFF_XPW;
  const ushort_t* dtwb  = wblob + OFF_DTW;
  __shared__ __align__(16) float xr[2][DP_];
  __shared__ __align__(16) float p1[2][DR_];
  __shared__ __align__(16) float rg[2][DR_];
  __shared__ __align__(16) float us[2][DR_];
  __shared__ float ps[4][2][128];
  __shared__ float prm[2][RK_ + 2 * N_];
  __shared__ float red[24];
  int tid = threadIdx.x;
  int r0 = blockIdx.x * 2;
  for (int i = tid; i < 2 * DP_; i += 512) xr[i / DP_][i % DP_] = pooled[(long)r0 * DP_ + i];
  __syncthreads();
  // ---- LN1
  float v0 = (tid < DP_) ? xr[0][tid] : 0.f;
  float v1 = (tid < DP_) ? xr[1][tid] : 0.f;
  float s0 = v0, s1v = v1;
  block_sum2(s0, s1v, red);
  float dv0 = (tid < DP_) ? (v0 - s0 * (1.f / DP_)) : 0.f;
  float dv1 = (tid < DP_) ? (v1 - s1v * (1.f / DP_)) : 0.f;
  float q0 = dv0 * dv0, q1 = dv1 * dv1;
  block_sum2(q0, q1, red);
  if (tid < DP_){
    float lw = ln1w[tid], lb = ln1b[tid];
    xr[0][tid] = dv0 * rsqrtf(q0 * (1.f / DP_) + 1e-5f) * lw + lb;
    xr[1][tid] = dv1 * rsqrtf(q1 * (1.f / DP_) + 1e-5f) * lw + lb;
  }
  __syncthreads();
  // ---- W1 + gelu (K=384; 16-deep weights, float4 activations, 4 acc chains)
  {
    float a0A = pb1[tid], a0B = 0.f, a1A = pb1[tid], a1B = 0.f;
    for (int k0 = 0; k0 < DP_; k0 += 16){
      ushort_t wv[16];
#pragma unroll
      for (int j = 0; j < 16; ++j) wv[j] = pw1b[(k0 + j) * DR_ + tid];
#pragma unroll
      for (int j4 = 0; j4 < 16; j4 += 4){
        float4 x0 = *(const float4*)(&xr[0][k0 + j4]);
        float4 x1 = *(const float4*)(&xr[1][k0 + j4]);
        float w0 = us2f(wv[j4]), w1f = us2f(wv[j4 + 1]);
        float w2f = us2f(wv[j4 + 2]), w3 = us2f(wv[j4 + 3]);
        if (j4 < 8){
          a0A = fmaf(x0.x, w0, a0A); a1A = fmaf(x1.x, w0, a1A);
          a0A = fmaf(x0.y, w1f, a0A); a1A = fmaf(x1.y, w1f, a1A);
          a0A = fmaf(x0.z, w2f, a0A); a1A = fmaf(x1.z, w2f, a1A);
          a0A = fmaf(x0.w, w3, a0A); a1A = fmaf(x1.w, w3, a1A);
        } else {
          a0B = fmaf(x0.x, w0, a0B); a1B = fmaf(x1.x, w0, a1B);
          a0B = fmaf(x0.y, w1f, a0B); a1B = fmaf(x1.y, w1f, a1B);
          a0B = fmaf(x0.z, w2f, a0B); a1B = fmaf(x1.z, w2f, a1B);
          a0B = fmaf(x0.w, w3, a0B); a1B = fmaf(x1.w, w3, a1B);
        }
      }
    }
    p1[0][tid] = gelu_f(a0A + a0B); p1[1][tid] = gelu_f(a1A + a1B);
  }
  __syncthreads();
  // ---- W2 (K=512, 4 acc chains)
  float qq0, qq1;
  {
    float a0A = pb2[tid], a0B = 0.f, a1A = pb2[tid], a1B = 0.f;
    for (int k0 = 0; k0 < DR_; k0 += 16){
      ushort_t wv[16];
#pragma unroll
      for (int j = 0; j < 16; ++j) wv[j] = pw2b[(k0 + j) * DR_ + tid];
#pragma unroll
      for (int j4 = 0; j4 < 16; j4 += 4){
        float4 x0 = *(const float4*)(&p1[0][k0 + j4]);
        float4 x1 = *(const float4*)(&p1[1][k0 + j4]);
        float w0 = us2f(wv[j4]), w1f = us2f(wv[j4 + 1]);
        float w2f = us2f(wv[j4 + 2]), w3 = us2f(wv[j4 + 3]);
        if (j4 < 8){
          a0A = fmaf(x0.x, w0, a0A); a1A = fmaf(x1.x, w0, a1A);
          a0A = fmaf(x0.y, w1f, a0A); a1A = fmaf(x1.y, w1f, a1A);
          a0A = fmaf(x0.z, w2f, a0A); a1A = fmaf(x1.z, w2f, a1A);
          a0A = fmaf(x0.w, w3, a0A); a1A = fmaf(x1.w, w3, a1A);
        } else {
          a0B = fmaf(x0.x, w0, a0B); a1B = fmaf(x1.x, w0, a1B);
          a0B = fmaf(x0.y, w1f, a0B); a1B = fmaf(x1.y, w1f, a1B);
          a0B = fmaf(x0.z, w2f, a0B); a1B = fmaf(x1.z, w2f, a1B);
          a0B = fmaf(x0.w, w3, a0B); a1B = fmaf(x1.w, w3, a1B);
        }
      }
    }
    qq0 = a0A + a0B; qq1 = a1A + a1B;
  }
  // ---- LN2 + nan fix + l2norm
  {
    float m0 = qq0, m1 = qq1;
    block_sum2(m0, m1, red);
    float d0 = qq0 - m0 * (1.f / DR_), d1 = qq1 - m1 * (1.f / DR_);
    float w0 = d0 * d0, w1 = d1 * d1;
    block_sum2(w0, w1, red);
    float lw = ln2w[tid], lb = ln2b[tid];
    float o0 = d0 * rsqrtf(w0 * (1.f / DR_) + 1e-5f) * lw + lb;
    float o1 = d1 * rsqrtf(w1 * (1.f / DR_) + 1e-5f) * lw + lb;
    if (isnan(o0)) o0 = 0.f; else if (isinf(o0)) o0 = (o0 > 0.f) ? 1.f : -1.f;
    if (isnan(o1)) o1 = 0.f; else if (isinf(o1)) o1 = (o1 > 0.f) ? 1.f : -1.f;
    float n0 = o0 * o0, n1 = o1 * o1;
    block_sum2(n0, n1, red);
    float r0v = o0 / fmaxf(sqrtf(n0), 1e-6f);
    float r1v = o1 / fmaxf(sqrtf(n1), 1e-6f);
    rg[0][tid] = r0v; rg[1][tid] = r1v;
    region[(long)r0 * DR_ + tid] = r0v;
    region[(long)(r0 + 1) * DR_ + tid] = r1v;
  }
  __syncthreads();
  // ---- in_proj (K=512; thread covers cols tid and tid+512; 8 acc chains)
  {
    float uaA0 = 0.f, uaB0 = 0.f, uaA1 = 0.f, uaB1 = 0.f;
    float zbA0 = 0.f, zbB0 = 0.f, zbA1 = 0.f, zbB1 = 0.f;
    for (int k0 = 0; k0 < DR_; k0 += 8){
      ushort_t w1v[8], w2v[8];
#pragma unroll
      for (int j = 0; j < 8; ++j){
        w1v[j] = inpwb[(k0 + j) * 1024 + tid];
        w2v[j] = inpwb[(k0 + j) * 1024 + tid + 512];
      }
#pragma unroll
      for (int j4 = 0; j4 < 8; j4 += 4){
        float4 x0 = *(const float4*)(&rg[0][k0 + j4]);
        float4 x1 = *(const float4*)(&rg[1][k0 + j4]);
        float xs0[4] = {x0.x, x0.y, x0.z, x0.w};
        float xs1[4] = {x1.x, x1.y, x1.z, x1.w};
        if (j4 == 0){
#pragma unroll
          for (int j = 0; j < 4; ++j){
            float wa = us2f(w1v[j]), wb = us2f(w2v[j]);
            uaA0 = fmaf(xs0[j], wa, uaA0); uaA1 = fmaf(xs1[j], wa, uaA1);
            zbA0 = fmaf(xs0[j], wb, zbA0); zbA1 = fmaf(xs1[j], wb, zbA1);
          }
        } else {
#pragma unroll
          for (int j = 0; j < 4; ++j){
            float wa = us2f(w1v[4 + j]), wb = us2f(w2v[4 + j]);
            uaB0 = fmaf(xs0[j], wa, uaB0); uaB1 = fmaf(xs1[j], wa, uaB1);
            zbB0 = fmaf(xs0[j], wb, zbB0); zbB1 = fmaf(xs1[j], wb, zbB1);
          }
        }
      }
    }
    float ua0 = uaA0 + uaB0, ua1 = uaA1 + uaB1;
    float zb0 = zbA0 + zbB0, zb1 = zbA1 + zbB1;
    us[0][tid] = ua0; us[1][tid] = ua1;
    uT[(long)tid * REGS + r0] = ua0;
    uT[(long)tid * REGS + r0 + 1] = ua1;
    zT[(long)tid * REGS + r0] = zb0;
    zT[(long)tid * REGS + r0 + 1] = zb1;
  }
  __syncthreads();
  // ---- x_proj: K-split 4 segs x 128 cols (4 acc chains)
  {
    int sseg = tid >> 7, c = tid & 127;
    float prA0 = 0.f, prB0 = 0.f, prA1 = 0.f, prB1 = 0.f;
    if (c < RK_ + 2 * N_){
      int kb = sseg * 128;
      for (int k0 = kb; k0 < kb + 128; k0 += 16){
        ushort_t wv[16];
#pragma unroll
        for (int j = 0; j < 16; ++j) wv[j] = xpwb[(k0 + j) * (RK_ + 2 * N_) + c];
#pragma unroll
        for (int j4 = 0; j4 < 16; j4 += 4){
          float4 x0 = *(const float4*)(&us[0][k0 + j4]);
          float4 x1 = *(const float4*)(&us[1][k0 + j4]);
          float w0 = us2f(wv[j4]), w1f = us2f(wv[j4 + 1]);
          float w2f = us2f(wv[j4 + 2]), w3 = us2f(wv[j4 + 3]);
          if (j4 < 8){
            prA0 = fmaf(x0.x, w0, prA0); prA1 = fmaf(x1.x, w0, prA1);
            prA0 = fmaf(x0.y, w1f, prA0); prA1 = fmaf(x1.y, w1f, prA1);
            prA0 = fmaf(x0.z, w2f, prA0); prA1 = fmaf(x1.z, w2f, prA1);
            prA0 = fmaf(x0.w, w3, prA0); prA1 = fmaf(x1.w, w3, prA1);
          } else {
            prB0 = fmaf(x0.x, w0, prB0); prB1 = fmaf(x1.x, w0, prB1);
            prB0 = fmaf(x0.y, w1f, prB0); prB1 = fmaf(x1.y, w1f, prB1);
            prB0 = fmaf(x0.z, w2f, prB0); prB1 = fmaf(x1.z, w2f, prB1);
            prB0 = fmaf(x0.w, w3, prB0); prB1 = fmaf(x1.w, w3, prB1);
          }
        }
      }
    }
    ps[sseg][0][c] = prA0 + prB0; ps[sseg][1][c] = prA1 + prB1;
  }
  __syncthreads();
  if (tid < 256){
    int rr2 = tid >> 7, cc = tid & 127;
    if (cc < RK_ + 2 * N_)
      prm[rr2][cc] = ps[0][rr2][cc] + ps[1][rr2][cc] + ps[2][rr2][cc] + ps[3][rr2][cc];
  }
  __syncthreads();
  // ---- dt head -> delta (transposed)
#pragma unroll
  for (int r = 0; r < 2; ++r){
    float aaA = dtb[tid], aaB = 0.f;
#pragma unroll
    for (int j = 0; j < RK_; j += 2){
      aaA = fmaf(prm[r][j], us2f(dtwb[j * DR_ + tid]), aaA);
      aaB = fmaf(prm[r][j + 1], us2f(dtwb[(j + 1) * DR_ + tid]), aaB);
    }
    float aa = aaA + aaB;
    float sp = (aa > 20.f) ? aa : log1pf(expf(aa));
    deltaT[(long)tid * REGS + r0 + r] = fminf(sp, 10.f);
  }
  if (tid < N_){
#pragma unroll
    for (int r = 0; r < 2; ++r){
      BmT[(long)tid * REGS + r0 + r] = prm[r][RK_ + tid];
      CmT[(long)tid * REGS + r0 + r] = prm[r][RK_ + N_ + tid];
    }
  }
}

// ---------------- R5: parallel-prefix selective scan (coalesced inputs) ----
__global__ __launch_bounds__(256) void k_scan(
    const float* __restrict__ deltaT, const float* __restrict__ uT,
    const float* __restrict__ zT, const float* __restrict__ BmT,
    const float* __restrict__ CmT, const float* __restrict__ alog,
    const float* __restrict__ Dp, float* __restrict__ ys){
  __shared__ float sAn[N_];
  __shared__ float sA[N_][4];
  __shared__ float sB[N_][4];
  int tid = threadIdx.x, lane = tid & 63, w = tid >> 6;
  int ch = blockIdx.x;
  int b = ch >> 9, d = ch & (DR_ - 1);
  if (tid < N_) sAn[tid] = -fminf(__expf(alog[d * N_ + tid]), 10000.f);
  long col = (long)b * R_ + tid;
  float dl = deltaT[(long)d * REGS + col];
  float uu = uT[(long)d * REGS + col];
  float zz = zT[(long)d * REGS + col];
  float Dd = Dp[d];
  float part = 0.f;
  __syncthreads();
  for (int nc = 0; nc < 6; ++nc){
    float bmv[8], cmv[8];
#pragma unroll
    for (int j = 0; j < 8; ++j){
      bmv[j] = BmT[(long)(nc * 8 + j) * REGS + col];
      cmv[j] = CmT[(long)(nc * 8 + j) * REGS + col];
    }
    float aA[8], aB[8];
#pragma unroll
    for (int j = 0; j < 8; ++j){
      int n = nc * 8 + j;
      float cc = fminf(fmaxf(dl * sAn[n], -30.f), 30.f);
      float a = exp2f(cc * 1.44269504f);
      float bv = dl * bmv[j] * uu;
#pragma unroll
      for (int s = 1; s < 64; s <<= 1){
        float a_sh = __shfl_up(a, (unsigned)s, 64);
        float b_sh = __shfl_up(bv, (unsigned)s, 64);
        float nb = fmaf(a, b_sh, bv);
        float na = a * a_sh;
        if (lane >= s){ bv = nb; a = na; }
      }
      aA[j] = a; aB[j] = bv;
      if (lane == 63){ sA[n][w] = a; sB[n][w] = bv; }
    }
    __syncthreads();
#pragma unroll
    for (int j = 0; j < 8; ++j){
      int n = nc * 8 + j;
      float hin = 0.f;
#pragma unroll
      for (int tt = 0; tt < 3; ++tt){
        if (tt < w) hin = sA[n][tt] * hin + sB[n][tt];
      }
      float h = fmaf(aA[j], hin, aB[j]);
      part = fmaf(cmv[j], h, part);
    }
    if (nc < 5) __syncthreads();
  }
  float yv = part + Dd * uu;
  float sz = zz / (1.f + __expf(-zz));
  ys[col * DR_ + d] = yv * sz;
}

// ---------------- R6: out_proj + residual + final LN + l2norm, 4 rows ------
__global__ __launch_bounds__(512) void k_out(
    const float* __restrict__ ys, const float* __restrict__ W,
    const float* __restrict__ region, const float* __restrict__ lnw,
    const float* __restrict__ lnb, float* __restrict__ outp,
    float* __restrict__ rt){
  __shared__ __align__(16) float yr[4][DR_];
  __shared__ float red[40];
  int tid = threadIdx.x;
  int r0 = blockIdx.x * 4;
  for (int i = tid; i < 4 * DR_; i += 512) yr[i >> 9][i & 511] = ys[(long)r0 * DR_ + i];
  __syncthreads();
  float y[4] = {0,0,0,0};
  for (int k0 = 0; k0 < DR_; k0 += 8){
    float wv[8];
#pragma unroll
    for (int j = 0; j < 8; ++j) wv[j] = W[(k0 + j) * DR_ + tid];
#pragma unroll
    for (int j4 = 0; j4 < 8; j4 += 4){
#pragma unroll
      for (int i = 0; i < 4; ++i){
        float4 x = *(const float4*)(&yr[i][k0 + j4]);
        y[i] = fmaf(x.x, wv[j4], y[i]);
        y[i] = fmaf(x.y, wv[j4 + 1], y[i]);
        y[i] = fmaf(x.z, wv[j4 + 2], y[i]);
        y[i] = fmaf(x.w, wv[j4 + 3], y[i]);
      }
    }
  }
  float v[4], t4[4];
#pragma unroll
  for (int i = 0; i < 4; ++i){
    if (isnan(y[i])) y[i] = 0.f; else if (isinf(y[i])) y[i] = (y[i] > 0.f) ? 1.f : -1.f;
    v[i] = region[(long)(r0 + i) * DR_ + tid] + y[i];
    t4[i] = v[i];
  }
  block_sum4(t4, red);
  float dv[4];
#pragma unroll
  for (int i = 0; i < 4; ++i){ dv[i] = v[i] - t4[i] * (1.f / DR_); t4[i] = dv[i] * dv[i]; }
  block_sum4(t4, red);
  float o[4];
  float lw = lnw[tid], lb = lnb[tid];
#pragma unroll
  for (int i = 0; i < 4; ++i){
    o[i] = dv[i] * rsqrtf(t4[i] * (1.f / DR_) + 1e-5f) * lw + lb;
    outp[(long)(r0 + i) * DR_ + tid] = o[i];
    t4[i] = o[i] * o[i];
  }
  block_sum4(t4, red);
#pragma unroll
  for (int i = 0; i < 4; ++i)
    rt[(long)(r0 + i) * DR_ + tid] = o[i] / fmaxf(sqrtf(t4[i]), 1e-6f);
}

// ---------------- R7: similarity losses, 4 query rows per block ------------
__global__ __launch_bounds__(512) void k_loss(
    const float* __restrict__ rt, const int* __restrict__ nearm,
    const int* __restrict__ farm, float* __restrict__ accum){
  __shared__ __align__(16) float ar[4][DR_];
  __shared__ float ps[2][4][256];
  __shared__ float wsum[8][4];
  int blk = blockIdx.x, tid = threadIdx.x;
  int b = blk >> 6, q0 = (blk & 63) * 4;
  const float* rtb = rt + (long)b * R_ * DR_;
  for (int i = tid; i < 4 * DR_; i += 512) ar[i >> 9][i & 511] = rtb[(long)q0 * DR_ + i];
  __syncthreads();
  int s = tid & 255, h = tid >> 8;
  const float* rsrow = rtb + (long)s * DR_ + h * 256;
  float dq[4] = {0.f, 0.f, 0.f, 0.f};
  for (int k = 0; k < 256; k += 4){
    float4 yv = *(const float4*)(rsrow + k);
#pragma unroll
    for (int q = 0; q < 4; ++q){
      float4 x = *(const float4*)(&ar[q][h * 256 + k]);
      dq[q] += x.x * yv.x + x.y * yv.y + x.z * yv.z + x.w * yv.w;
    }
  }
#pragma unroll
  for (int q = 0; q < 4; ++q) ps[h][q][s] = dq[q];
  __syncthreads();
  float nl = 0.f, fl = 0.f, nc = 0.f, fc = 0.f;
  if (tid < 256){
#pragma unroll
    for (int q = 0; q < 4; ++q){
      float dot = ps[0][q][tid] + ps[1][q][tid];
      int nm = nearm[(q0 + q) * R_ + tid], fm = farm[(q0 + q) * R_ + tid];
      if (nm){ nl += 1.f - dot; if (b == 0) nc += 1.f; }
      if (fm){ fl += fmaxf(dot - 0.2f, 0.f); if (b == 0) fc += 1.f; }
    }
  }
  nl = wred_sum(nl); fl = wred_sum(fl); nc = wred_sum(nc); fc = wred_sum(fc);
  int w = tid >> 6, lane = tid & 63;
  if (lane == 0){ wsum[w][0] = nl; wsum[w][1] = fl; wsum[w][2] = nc; wsum[w][3] = fc; }
  __syncthreads();
  if (tid == 0){
    float a0 = 0, a1 = 0, a2 = 0, a3 = 0;
    for (int i = 0; i < 8; i++){ a0 += wsum[i][0]; a1 += wsum[i][1]; a2 += wsum[i][2]; a3 += wsum[i][3]; }
    atomicAdd(&accum[0], a0); atomicAdd(&accum[1], a1);
    if (b == 0){ atomicAdd(&accum[2], a2); atomicAdd(&accum[3], a3); }
  }
}

__global__ void k_final(const float* __restrict__ accum, float* __restrict__ outp){
  if (threadIdx.x == 0){
    float loss = accum[0] / fmaxf(accum[2], 1.f) + accum[1] / fmaxf(accum[3], 1.f);
    outp[REGS * DR_] = loss;
  }
}

extern "C" void kernel_launch(void* const* d_in, const int* in_sizes, int n_in,
                              void* d_out, int out_size, void* d_ws, size_t ws_size,
                              hipStream_t stream){
  const float* pt    = (const float*)d_in[0];
  const int*   pmask = (const int*)d_in[1];
  const int*   nearm = (const int*)d_in[2];
  const int*   farm  = (const int*)d_in[3];
  const float* lp    = (const float*)d_in[4];
  const float* glnw  = (const float*)d_in[5];
  const float* glnb  = (const float*)d_in[6];
  const float* gw1   = (const float*)d_in[7];
  const float* gb1   = (const float*)d_in[8];
  const float* gw2   = (const float*)d_in[9];
  const float* pln1w = (const float*)d_in[11];
  const float* pln1b = (const float*)d_in[12];
  const float* pw1   = (const float*)d_in[13];
  const float* pb1   = (const float*)d_in[14];
  const float* pw2   = (const float*)d_in[15];
  const float* pb2   = (const float*)d_in[16];
  const float* pln2w = (const float*)d_in[17];
  const float* pln2b = (const float*)d_in[18];
  const float* inpw  = (const float*)d_in[19];
  const float* xpw   = (const float*)d_in[20];
  const float* dtw   = (const float*)d_in[21];
  const float* dtb   = (const float*)d_in[22];
  const float* alog  = (const float*)d_in[23];
  const float* dpar  = (const float*)d_in[24];
  const float* opw   = (const float*)d_in[25];
  const float* slnw  = (const float*)d_in[26];
  const float* slnb  = (const float*)d_in[27];

  char* ws = (char*)d_ws;
  size_t off = 0;
  auto alloc = [&](size_t bytes){ size_t o = off; off += (bytes + 255) & ~(size_t)255; return o; };
  ushort_t* W1pT  = (ushort_t*)(ws + alloc((size_t)DR_ * DP_ * 2));
  float* s1     = (float*)(ws + alloc(DR_ * 4));
  float* b1p    = (float*)(ws + alloc(DR_ * 4));
  ushort_t* wblob = (ushort_t*)(ws + alloc((size_t)NW_TOT * 2));
  ushort_t* xb  = (ushort_t*)(ws + alloc((size_t)MROWS * DP_ * 2));
  float* mu     = (float*)(ws + alloc((size_t)MROWS * 4));
  float* rsg    = (float*)(ws + alloc((size_t)MROWS * 4));
  float* pooled = (float*)(ws + alloc((size_t)REGS * DP_ * 4));
  float* region = (float*)(ws + alloc((size_t)REGS * DR_ * 4));
  float* uT     = (float*)(ws + alloc((size_t)REGS * DR_ * 4));
  float* zT     = (float*)(ws + alloc((size_t)REGS * DR_ * 4));
  float* deltaT = (float*)(ws + alloc((size_t)REGS * DR_ * 4));
  float* BmT    = (float*)(ws + alloc((size_t)REGS * N_ * 4));
  float* CmT    = (float*)(ws + alloc((size_t)REGS * N_ * 4));
  float* ys     = (float*)(ws + alloc((size_t)REGS * DR_ * 4));
  float* rt     = (float*)(ws + alloc((size_t)REGS * DR_ * 4));
  float* accum  = (float*)(ws + alloc(4 * 4));

  float* outp = (float*)d_out;

  k_prep<<<dim3(8), dim3(512), 0, stream>>>(gw1, glnw, glnb, gb1, W1pT, s1, b1p, accum);
  k_cast<<<dim3((NW_TOT / 4 + 511) / 512), dim3(512), 0, stream>>>(pw1, pw2, inpw, xpw, dtw, wblob);
  k_xform<<<dim3(MROWS / 8), dim3(512), 0, stream>>>(pt, lp, xb, mu, rsg);
  k_gate_pool<<<dim3(MROWS / 128), dim3(1024), 0, stream>>>(xb, W1pT, mu, rsg, s1, b1p, gw2, pmask, pooled);
  k_region<<<dim3(REGS / 2), dim3(512), 0, stream>>>(pooled, pln1w, pln1b, wblob, pb1, pb2, pln2w, pln2b,
                                                     dtb, region, uT, zT, deltaT, BmT, CmT);
  k_scan<<<dim3(B_ * DR_), dim3(256), 0, stream>>>(deltaT, uT, zT, BmT, CmT, alog, dpar, ys);
  k_out<<<dim3(REGS / 4), dim3(512), 0, stream>>>(ys, opw, region, slnw, slnb, outp, rt);
  k_loss<<<dim3(REGS / 4), dim3(512), 0, stream>>>(rt, nearm, farm, accum);
  k_final<<<dim3(1), dim3(64), 0, stream>>>(accum, outp);
}

// Round 20
// 308.385 us; speedup vs baseline: 1.5717x; 1.5717x over previous
//
#include <hip/hip_runtime.h>
#include <hip/hip_bf16.h>
#include <math.h>

#define B_ 4
#define R_ 256
#define P_ 64
#define DP_ 384
#define DR_ 512
#define N_ 48
#define RK_ 24
#define MROWS (B_*R_*P_)   /* 65536 */
#define REGS  (B_*R_)      /* 1024  */

typedef unsigned short ushort_t;
typedef __attribute__((ext_vector_type(8))) short bf16x8;
typedef __attribute__((ext_vector_type(4))) float f32x4;

#define GLOAD16(g, l) __builtin_amdgcn_global_load_lds( \
    (const __attribute__((address_space(1))) unsigned int*)(g), \
    (__attribute__((address_space(3))) unsigned int*)(l), 16, 0, 0)

// bf16 weight blob segment offsets (elements) — [k][n] layout (coalesced)
#define OFF_PW1  0
#define OFF_PW2  196608
#define OFF_INPW 458752
#define OFF_XPW  983040
#define OFF_DTW  1044480
#define NW_TOT   1056768

__device__ __forceinline__ float us2f(unsigned short u){
  union { unsigned int i; float f; } x; x.i = ((unsigned int)u) << 16; return x.f;
}
__device__ __forceinline__ unsigned short f2us(float f){
  __hip_bfloat16 h = __float2bfloat16(f);
  return *reinterpret_cast<unsigned short*>(&h);
}
// fast gelu: sigmoid approximation x*sigmoid(1.702x) (|err| < 0.02 abs)
__device__ __forceinline__ float gelu_f(float x){
  return x / (1.0f + __expf(-1.702f * x));
}
__device__ __forceinline__ float wred_sum(float v){
#pragma unroll
  for (int m = 1; m < 64; m <<= 1) v += __shfl_xor(v, m, 64);
  return v;
}
// 4 simultaneous block-wide sums (512-thread blocks); s >= 40 floats
__device__ __forceinline__ void block_sum4(float v[4], float* s){
  int lane = threadIdx.x & 63, wid = threadIdx.x >> 6;
#pragma unroll
  for (int i = 0; i < 4; ++i){
    float x = v[i];
#pragma unroll
    for (int m = 1; m < 64; m <<= 1) x += __shfl_xor(x, m, 64);
    if (lane == 0) s[wid * 4 + i] = x;
  }
  __syncthreads();
  if (threadIdx.x < 4){
    float t = 0.f;
    for (int t2 = 0; t2 < 8; ++t2) t += s[t2 * 4 + threadIdx.x];
    s[32 + threadIdx.x] = t;
  }
  __syncthreads();
#pragma unroll
  for (int i = 0; i < 4; ++i) v[i] = s[32 + i];
  __syncthreads();
}
// 2 simultaneous block-wide sums (512-thread blocks); s >= 18 floats
__device__ __forceinline__ void block_sum2(float& a, float& b, float* s){
  int lane = threadIdx.x & 63, wid = threadIdx.x >> 6;
  float x = a, y = b;
#pragma unroll
  for (int m = 1; m < 64; m <<= 1){ x += __shfl_xor(x, m, 64); y += __shfl_xor(y, m, 64); }
  if (lane == 0){ s[wid * 2] = x; s[wid * 2 + 1] = y; }
  __syncthreads();
  if (threadIdx.x < 2){
    float t = 0.f;
    for (int j = 0; j < 8; ++j) t += s[j * 2 + threadIdx.x];
    s[16 + threadIdx.x] = t;
  }
  __syncthreads();
  a = s[16]; b = s[17];
  __syncthreads();
}

// ---------------- C0: weight prep, parallel. 8 blocks x 512 ----------------
__global__ __launch_bounds__(512) void k_prep(
    const float* __restrict__ gw1, const float* __restrict__ glnw,
    const float* __restrict__ glnb, const float* __restrict__ gb1,
    ushort_t* __restrict__ W1pT, float* __restrict__ s1,
    float* __restrict__ b1p, float* __restrict__ accum){
  __shared__ float pss[8][64], psb[8][64];
  int tid = threadIdx.x, seg = tid >> 6, nl = tid & 63;
  int n = blockIdx.x * 64 + nl;
  if (blockIdx.x == 0 && tid < 4) accum[tid] = 0.f;
  float s = 0.f, sb = 0.f;
  int k0 = seg * 48;
  for (int i = 0; i < 48; ++i){
    int k = k0 + i;
    float w1 = gw1[k * DR_ + n];
    float v = glnw[k] * w1;
    unsigned short vr = f2us(v);
    s  += us2f(vr);
    sb += glnb[k] * w1;
    W1pT[(size_t)n * DP_ + k] = vr;
  }
  pss[seg][nl] = s; psb[seg][nl] = sb;
  __syncthreads();
  if (tid < 64){
    float ts = 0.f, tb = 0.f;
    for (int j = 0; j < 8; ++j){ ts += pss[j][tid]; tb += psb[j][tid]; }
    s1[blockIdx.x * 64 + tid] = ts;
    b1p[blockIdx.x * 64 + tid] = gb1[blockIdx.x * 64 + tid] + tb;
  }
}

// ---------------- C1: cast region-chain weights f32 -> bf16 blob -----------
__global__ __launch_bounds__(512) void k_cast(
    const float* __restrict__ pw1, const float* __restrict__ pw2,
    const float* __restrict__ inpw, const float* __restrict__ xpw,
    const float* __restrict__ dtw, ushort_t* __restrict__ dst){
  int i = (blockIdx.x * 512 + threadIdx.x) * 4;
  if (i >= NW_TOT) return;
  const float* s; int off;
  if (i < OFF_PW2){ s = pw1; off = OFF_PW1; }
  else if (i < OFF_INPW){ s = pw2; off = OFF_PW2; }
  else if (i < OFF_XPW){ s = inpw; off = OFF_INPW; }
  else if (i < OFF_DTW){ s = xpw; off = OFF_XPW; }
  else { s = dtw; off = OFF_DTW; }
  float4 v = *(const float4*)(s + (i - off));
  ushort_t* d = dst + i;
  d[0] = f2us(v.x); d[1] = f2us(v.y); d[2] = f2us(v.z); d[3] = f2us(v.w);
}

// ---------------- S0: xb = bf16(pt + lp) + LN stats. 8 rows/block ----------
__global__ __launch_bounds__(512) void k_xform(
    const float* __restrict__ pt, const float* __restrict__ lp,
    ushort_t* __restrict__ xb, float* __restrict__ mu, float* __restrict__ rsg){
  int tid = threadIdx.x, w = tid >> 6, lane = tid & 63;
  size_t r = (size_t)blockIdx.x * 8 + w;
  int p = (int)(r & (P_ - 1));
  const float* xr = pt + r * DP_ + lane * 6;
  const float* lr = lp + (size_t)p * DP_ + lane * 6;
  float x[6];
  float s = 0.f, ss = 0.f;
#pragma unroll
  for (int i = 0; i < 6; i += 2){
    float2 a = *(const float2*)(xr + i);
    float2 b = *(const float2*)(lr + i);
    x[i] = a.x + b.x; x[i + 1] = a.y + b.y;
  }
#pragma unroll
  for (int i = 0; i < 6; ++i){ s += x[i]; ss += x[i] * x[i]; }
  s = wred_sum(s); ss = wred_sum(ss);
  if (lane == 0){
    float m = s * (1.f / DP_);
    float var = ss * (1.f / DP_) - m * m;
    mu[r] = m;
    rsg[r] = rsqrtf(var + 1e-5f);
  }
  ushort_t* xw = xb + r * DP_ + lane * 6;
#pragma unroll
  for (int i = 0; i < 6; i += 2){
    ushort2 u2; u2.x = f2us(x[i]); u2.y = f2us(x[i + 1]);
    *(ushort2*)(xw + i) = u2;
  }
}

// ---- P2 fused: gate GEMM (BM=128, 16 waves) + folded LN + gelu + logit
//      (contention-free LDS-partial reduce) + softmax + attention pooling.
__global__ __launch_bounds__(1024, 4) void k_gate_pool(
    const ushort_t* __restrict__ xb,   // (65536 x 384) bf16
    const ushort_t* __restrict__ BT,   // W1pT (512 x 384) bf16
    const float* __restrict__ mu, const float* __restrict__ rsg,
    const float* __restrict__ s1, const float* __restrict__ b1p,
    const float* __restrict__ w2, const int* __restrict__ pmask,
    float* __restrict__ pooled){
  __shared__ __align__(16) ushort_t Abuf[2][128 * 64];   // 32 KB; pool scratch later
  __shared__ float wpart[16][128];                       // 8 KB
  __shared__ float logit_lds[128];
  __shared__ float smu[128], srs[128];
  __shared__ float attn2[2][64];
  int tid = threadIdx.x;
  int lane = tid & 63, w = tid >> 6;        // w: 0..15
  int t = lane & 15, g = lane >> 4;
  long r0 = (long)blockIdx.x * 128;
  if (tid < 128){
    smu[tid] = mu[r0 + tid];
    srs[tid] = rsg[r0 + tid];
  }

  f32x4 acc[8][2];
#pragma unroll
  for (int m = 0; m < 8; ++m)
#pragma unroll
    for (int n = 0; n < 2; ++n) acc[m][n] = (f32x4){0.f, 0.f, 0.f, 0.f};

  // staging: wave w stages rows w*8..w*8+7 (whole 128x64 tile in 1 instr)
  int ro = lane >> 3, c = lane & 7;
  int srow = (w << 3) + ro;
  const ushort_t* asrc = xb + (size_t)(r0 + srow) * DP_ + ((c ^ (srow & 7)) << 3);

  GLOAD16(asrc, Abuf[0] + (w << 9));
  __syncthreads();                    // buf0 ready

  for (int kt = 0; kt < 6; ++kt){
    int cb = kt & 1;
    if (kt < 5) GLOAD16(asrc + (kt + 1) * 64, Abuf[cb ^ 1] + (w << 9));
    // B fragments: wave owns cols w*32 + n*16 + t
    bf16x8 bfr[2][2];
#pragma unroll
    for (int kk = 0; kk < 2; ++kk)
#pragma unroll
      for (int n = 0; n < 2; ++n){
        int col = w * 32 + n * 16 + t;
        bfr[kk][n] = *(const bf16x8*)(BT + (size_t)col * DP_ + kt * 64 + (kk * 4 + g) * 8);
      }
#pragma unroll
    for (int kk = 0; kk < 2; ++kk){
      int ch = kk * 4 + g;
#pragma unroll
      for (int m = 0; m < 8; ++m){
        int row = m * 16 + t;
        bf16x8 af = *(const bf16x8*)(Abuf[cb] + row * 64 + ((ch ^ (row & 7)) << 3));
#pragma unroll
        for (int n = 0; n < 2; ++n)
          acc[m][n] = __builtin_amdgcn_mfma_f32_16x16x32_bf16(af, bfr[kk][n], acc[m][n], 0, 0, 0);
      }
    }
    __syncthreads();                  // next buf staged; current reads done
  }

  // epilogue: folded LN + gelu + per-wave partials (no atomics).
  // shuffles at width 16 (masks 1..8 stay in a row -> DPP, no DS ops)
  float w2c[2], s1c[2], b1c[2];
#pragma unroll
  for (int n = 0; n < 2; ++n){
    int col = w * 32 + n * 16 + t;
    w2c[n] = w2[col]; s1c[n] = s1[col]; b1c[n] = b1p[col];
  }
#pragma unroll
  for (int m = 0; m < 8; ++m){
#pragma unroll
    for (int j = 0; j < 4; ++j){
      int rl = m * 16 + g * 4 + j;
      float mur = smu[rl], rs = srs[rl];
      float part = 0.f;
#pragma unroll
      for (int n = 0; n < 2; ++n){
        float gp = rs * acc[m][n][j] - mur * rs * s1c[n] + b1c[n];
        part += gelu_f(gp) * w2c[n];
      }
#pragma unroll
      for (int msk = 1; msk < 16; msk <<= 1) part += __shfl_xor(part, msk, 16);
      if (t == 0) wpart[w][rl] = part;
    }
  }
  __syncthreads();
  if (tid < 128){
    float s = 0.f;
#pragma unroll
    for (int wi = 0; wi < 16; ++wi) s += wpart[wi][tid];
    logit_lds[tid] = s;               // gate_b2 cancels in softmax
  }
  __syncthreads();

  // masked softmax for each of the 2 regions (one full wave per half)
  int half = tid >> 9, lt = tid & 511;
  long rr0 = r0 + half * 64;
  if (lt < 64){
    int mk = pmask[rr0 + lt];
    float lv = logit_lds[half * 64 + lt];
    float lm = mk ? lv : -3.4e38f;
    float M = lm;
#pragma unroll
    for (int m2 = 1; m2 < 64; m2 <<= 1) M = fmaxf(M, __shfl_xor(M, m2, 64));
    float e = mk ? __expf(lv - M) : 0.f;
    float S = e;
#pragma unroll
    for (int m2 = 1; m2 < 64; m2 <<= 1) S += __shfl_xor(S, m2, 64);
    float a = (S > 0.f) ? e / S : 0.f;
    float S2 = a;
#pragma unroll
    for (int m2 = 1; m2 < 64; m2 <<= 1) S2 += __shfl_xor(S2, m2, 64);
    attn2[half][lt] = a / fmaxf(S2, 1e-6f);
  }
  __syncthreads();

  // attention pooling (xb L2/L3-hot); Abuf reused as f32 scratch [2][8][384]
  float* pbuf = (float*)Abuf;
  if (lt < 384){
    int pg = lt / 48, cc = lt % 48;
    float a8[8] = {0,0,0,0,0,0,0,0};
#pragma unroll
    for (int i = 0; i < 8; ++i){
      int p = pg + i * 8;
      bf16x8 v = *(const bf16x8*)(xb + (size_t)(rr0 + p) * DP_ + cc * 8);
      float ap = attn2[half][p];
#pragma unroll
      for (int j = 0; j < 8; ++j) a8[j] = fmaf(ap, us2f((unsigned short)v[j]), a8[j]);
    }
#pragma unroll
    for (int j = 0; j < 8; ++j) pbuf[(half * 8 + pg) * DP_ + cc * 8 + j] = a8[j];
  }
  __syncthreads();
  if (lt < 384){
    float s = 0.f;
#pragma unroll
    for (int g2 = 0; g2 < 8; ++g2) s += pbuf[(half * 8 + g2) * DP_ + lt];
    pooled[(long)(2 * blockIdx.x + half) * DP_ + lt] = s;
  }
}

// ---- R1+R3+R4 fused: region MLP -> in_proj -> x_proj. 2 rows/block,
//      512 blocks. Coalesced [k][n] weights; SPLIT accumulator chains (ILP).
__global__ __launch_bounds__(512, 4) void k_region(
    const float* __restrict__ pooled,
    const float* __restrict__ ln1w, const float* __restrict__ ln1b,
    const ushort_t* __restrict__ wblob, const float* __restrict__ pb1,
    const float* __restrict__ pb2,
    const float* __restrict__ ln2w, const float* __restrict__ ln2b,
    const float* __restrict__ dtb,
    float* __restrict__ region, float* __restrict__ uT, float* __restrict__ zT,
    float* __restrict__ deltaT, float* __restrict__ BmT, float* __restrict__ CmT){
  const ushort_t* pw1b  = wblob + OFF_PW1;
  const ushort_t* pw2b  = wblob + OFF_PW2;
  const ushort_t* inpwb = wblob + OFF_INPW;
  const ushort_t* xpwb  = wblob + OFF_XPW;
  const ushort_t* dtwb  = wblob + OFF_DTW;
  __shared__ __align__(16) float xr[2][DP_];
  __shared__ __align__(16) float p1[2][DR_];
  __shared__ __align__(16) float rg[2][DR_];
  __shared__ __align__(16) float us[2][DR_];
  __shared__ float ps[4][2][128];
  __shared__ float prm[2][RK_ + 2 * N_];
  __shared__ float red[24];
  int tid = threadIdx.x;
  int r0 = blockIdx.x * 2;
  for (int i = tid; i < 2 * DP_; i += 512) xr[i / DP_][i % DP_] = pooled[(long)r0 * DP_ + i];
  __syncthreads();
  // ---- LN1
  float v0 = (tid < DP_) ? xr[0][tid] : 0.f;
  float v1 = (tid < DP_) ? xr[1][tid] : 0.f;
  float s0 = v0, s1v = v1;
  block_sum2(s0, s1v, red);
  float dv0 = (tid < DP_) ? (v0 - s0 * (1.f / DP_)) : 0.f;
  float dv1 = (tid < DP_) ? (v1 - s1v * (1.f / DP_)) : 0.f;
  float q0 = dv0 * dv0, q1 = dv1 * dv1;
  block_sum2(q0, q1, red);
  if (tid < DP_){
    float lw = ln1w[tid], lb = ln1b[tid];
    xr[0][tid] = dv0 * rsqrtf(q0 * (1.f / DP_) + 1e-5f) * lw + lb;
    xr[1][tid] = dv1 * rsqrtf(q1 * (1.f / DP_) + 1e-5f) * lw + lb;
  }
  __syncthreads();
  // ---- W1 + gelu (K=384; 16-deep weights, float4 activations, 4 acc chains)
  {
    float a0A = pb1[tid], a0B = 0.f, a1A = pb1[tid], a1B = 0.f;
    for (int k0 = 0; k0 < DP_; k0 += 16){
      ushort_t wv[16];
#pragma unroll
      for (int j = 0; j < 16; ++j) wv[j] = pw1b[(k0 + j) * DR_ + tid];
#pragma unroll
      for (int j4 = 0; j4 < 16; j4 += 4){
        float4 x0 = *(const float4*)(&xr[0][k0 + j4]);
        float4 x1 = *(const float4*)(&xr[1][k0 + j4]);
        float w0 = us2f(wv[j4]), w1f = us2f(wv[j4 + 1]);
        float w2f = us2f(wv[j4 + 2]), w3 = us2f(wv[j4 + 3]);
        if (j4 < 8){
          a0A = fmaf(x0.x, w0, a0A); a1A = fmaf(x1.x, w0, a1A);
          a0A = fmaf(x0.y, w1f, a0A); a1A = fmaf(x1.y, w1f, a1A);
          a0A = fmaf(x0.z, w2f, a0A); a1A = fmaf(x1.z, w2f, a1A);
          a0A = fmaf(x0.w, w3, a0A); a1A = fmaf(x1.w, w3, a1A);
        } else {
          a0B = fmaf(x0.x, w0, a0B); a1B = fmaf(x1.x, w0, a1B);
          a0B = fmaf(x0.y, w1f, a0B); a1B = fmaf(x1.y, w1f, a1B);
          a0B = fmaf(x0.z, w2f, a0B); a1B = fmaf(x1.z, w2f, a1B);
          a0B = fmaf(x0.w, w3, a0B); a1B = fmaf(x1.w, w3, a1B);
        }
      }
    }
    p1[0][tid] = gelu_f(a0A + a0B); p1[1][tid] = gelu_f(a1A + a1B);
  }
  __syncthreads();
  // ---- W2 (K=512, 4 acc chains)
  float qq0, qq1;
  {
    float a0A = pb2[tid], a0B = 0.f, a1A = pb2[tid], a1B = 0.f;
    for (int k0 = 0; k0 < DR_; k0 += 16){
      ushort_t wv[16];
#pragma unroll
      for (int j = 0; j < 16; ++j) wv[j] = pw2b[(k0 + j) * DR_ + tid];
#pragma unroll
      for (int j4 = 0; j4 < 16; j4 += 4){
        float4 x0 = *(const float4*)(&p1[0][k0 + j4]);
        float4 x1 = *(const float4*)(&p1[1][k0 + j4]);
        float w0 = us2f(wv[j4]), w1f = us2f(wv[j4 + 1]);
        float w2f = us2f(wv[j4 + 2]), w3 = us2f(wv[j4 + 3]);
        if (j4 < 8){
          a0A = fmaf(x0.x, w0, a0A); a1A = fmaf(x1.x, w0, a1A);
          a0A = fmaf(x0.y, w1f, a0A); a1A = fmaf(x1.y, w1f, a1A);
          a0A = fmaf(x0.z, w2f, a0A); a1A = fmaf(x1.z, w2f, a1A);
          a0A = fmaf(x0.w, w3, a0A); a1A = fmaf(x1.w, w3, a1A);
        } else {
          a0B = fmaf(x0.x, w0, a0B); a1B = fmaf(x1.x, w0, a1B);
          a0B = fmaf(x0.y, w1f, a0B); a1B = fmaf(x1.y, w1f, a1B);
          a0B = fmaf(x0.z, w2f, a0B); a1B = fmaf(x1.z, w2f, a1B);
          a0B = fmaf(x0.w, w3, a0B); a1B = fmaf(x1.w, w3, a1B);
        }
      }
    }
    qq0 = a0A + a0B; qq1 = a1A + a1B;
  }
  // ---- LN2 + nan fix + l2norm
  {
    float m0 = qq0, m1 = qq1;
    block_sum2(m0, m1, red);
    float d0 = qq0 - m0 * (1.f / DR_), d1 = qq1 - m1 * (1.f / DR_);
    float w0 = d0 * d0, w1 = d1 * d1;
    block_sum2(w0, w1, red);
    float lw = ln2w[tid], lb = ln2b[tid];
    float o0 = d0 * rsqrtf(w0 * (1.f / DR_) + 1e-5f) * lw + lb;
    float o1 = d1 * rsqrtf(w1 * (1.f / DR_) + 1e-5f) * lw + lb;
    if (isnan(o0)) o0 = 0.f; else if (isinf(o0)) o0 = (o0 > 0.f) ? 1.f : -1.f;
    if (isnan(o1)) o1 = 0.f; else if (isinf(o1)) o1 = (o1 > 0.f) ? 1.f : -1.f;
    float n0 = o0 * o0, n1 = o1 * o1;
    block_sum2(n0, n1, red);
    float r0v = o0 / fmaxf(sqrtf(n0), 1e-6f);
    float r1v = o1 / fmaxf(sqrtf(n1), 1e-6f);
    rg[0][tid] = r0v; rg[1][tid] = r1v;
    region[(long)r0 * DR_ + tid] = r0v;
    region[(long)(r0 + 1) * DR_ + tid] = r1v;
  }
  __syncthreads();
  // ---- in_proj (K=512; thread covers cols tid and tid+512; 8 acc chains)
  {
    float uaA0 = 0.f, uaB0 = 0.f, uaA1 = 0.f, uaB1 = 0.f;
    float zbA0 = 0.f, zbB0 = 0.f, zbA1 = 0.f, zbB1 = 0.f;
    for (int k0 = 0; k0 < DR_; k0 += 8){
      ushort_t w1v[8], w2v[8];
#pragma unroll
      for (int j = 0; j < 8; ++j){
        w1v[j] = inpwb[(k0 + j) * 1024 + tid];
        w2v[j] = inpwb[(k0 + j) * 1024 + tid + 512];
      }
#pragma unroll
      for (int j4 = 0; j4 < 8; j4 += 4){
        float4 x0 = *(const float4*)(&rg[0][k0 + j4]);
        float4 x1 = *(const float4*)(&rg[1][k0 + j4]);
        float xs0[4] = {x0.x, x0.y, x0.z, x0.w};
        float xs1[4] = {x1.x, x1.y, x1.z, x1.w};
        if (j4 == 0){
#pragma unroll
          for (int j = 0; j < 4; ++j){
            float wa = us2f(w1v[j]), wb = us2f(w2v[j]);
            uaA0 = fmaf(xs0[j], wa, uaA0); uaA1 = fmaf(xs1[j], wa, uaA1);
            zbA0 = fmaf(xs0[j], wb, zbA0); zbA1 = fmaf(xs1[j], wb, zbA1);
          }
        } else {
#pragma unroll
          for (int j = 0; j < 4; ++j){
            float wa = us2f(w1v[4 + j]), wb = us2f(w2v[4 + j]);
            uaB0 = fmaf(xs0[j], wa, uaB0); uaB1 = fmaf(xs1[j], wa, uaB1);
            zbB0 = fmaf(xs0[j], wb, zbB0); zbB1 = fmaf(xs1[j], wb, zbB1);
          }
        }
      }
    }
    float ua0 = uaA0 + uaB0, ua1 = uaA1 + uaB1;
    float zb0 = zbA0 + zbB0, zb1 = zbA1 + zbB1;
    us[0][tid] = ua0; us[1][tid] = ua1;
    uT[(long)tid * REGS + r0] = ua0;
    uT[(long)tid * REGS + r0 + 1] = ua1;
    zT[(long)tid * REGS + r0] = zb0;
    zT[(long)tid * REGS + r0 + 1] = zb1;
  }
  __syncthreads();
  // ---- x_proj: K-split 4 segs x 128 cols (4 acc chains)
  {
    int sseg = tid >> 7, c = tid & 127;
    float prA0 = 0.f, prB0 = 0.f, prA1 = 0.f, prB1 = 0.f;
    if (c < RK_ + 2 * N_){
      int kb = sseg * 128;
      for (int k0 = kb; k0 < kb + 128; k0 += 16){
        ushort_t wv[16];
#pragma unroll
        for (int j = 0; j < 16; ++j) wv[j] = xpwb[(k0 + j) * (RK_ + 2 * N_) + c];
#pragma unroll
        for (int j4 = 0; j4 < 16; j4 += 4){
          float4 x0 = *(const float4*)(&us[0][k0 + j4]);
          float4 x1 = *(const float4*)(&us[1][k0 + j4]);
          float w0 = us2f(wv[j4]), w1f = us2f(wv[j4 + 1]);
          float w2f = us2f(wv[j4 + 2]), w3 = us2f(wv[j4 + 3]);
          if (j4 < 8){
            prA0 = fmaf(x0.x, w0, prA0); prA1 = fmaf(x1.x, w0, prA1);
            prA0 = fmaf(x0.y, w1f, prA0); prA1 = fmaf(x1.y, w1f, prA1);
            prA0 = fmaf(x0.z, w2f, prA0); prA1 = fmaf(x1.z, w2f, prA1);
            prA0 = fmaf(x0.w, w3, prA0); prA1 = fmaf(x1.w, w3, prA1);
          } else {
            prB0 = fmaf(x0.x, w0, prB0); prB1 = fmaf(x1.x, w0, prB1);
            prB0 = fmaf(x0.y, w1f, prB0); prB1 = fmaf(x1.y, w1f, prB1);
            prB0 = fmaf(x0.z, w2f, prB0); prB1 = fmaf(x1.z, w2f, prB1);
            prB0 = fmaf(x0.w, w3, prB0); prB1 = fmaf(x1.w, w3, prB1);
          }
        }
      }
    }
    ps[sseg][0][c] = prA0 + prB0; ps[sseg][1][c] = prA1 + prB1;
  }
  __syncthreads();
  if (tid < 256){
    int rr2 = tid >> 7, cc = tid & 127;
    if (cc < RK_ + 2 * N_)
      prm[rr2][cc] = ps[0][rr2][cc] + ps[1][rr2][cc] + ps[2][rr2][cc] + ps[3][rr2][cc];
  }
  __syncthreads();
  // ---- dt head -> delta (transposed)
#pragma unroll
  for (int r = 0; r < 2; ++r){
    float aaA = dtb[tid], aaB = 0.f;
#pragma unroll
    for (int j = 0; j < RK_; j += 2){
      aaA = fmaf(prm[r][j], us2f(dtwb[j * DR_ + tid]), aaA);
      aaB = fmaf(prm[r][j + 1], us2f(dtwb[(j + 1) * DR_ + tid]), aaB);
    }
    float aa = aaA + aaB;
    float sp = (aa > 20.f) ? aa : log1pf(expf(aa));
    deltaT[(long)tid * REGS + r0 + r] = fminf(sp, 10.f);
  }
  if (tid < N_){
#pragma unroll
    for (int r = 0; r < 2; ++r){
      BmT[(long)tid * REGS + r0 + r] = prm[r][RK_ + tid];
      CmT[(long)tid * REGS + r0 + r] = prm[r][RK_ + N_ + tid];
    }
  }
}

// ---------------- R5: parallel-prefix selective scan (coalesced inputs) ----
__global__ __launch_bounds__(256) void k_scan(
    const float* __restrict__ deltaT, const float* __restrict__ uT,
    const float* __restrict__ zT, const float* __restrict__ BmT,
    const float* __restrict__ CmT, const float* __restrict__ alog,
    const float* __restrict__ Dp, float* __restrict__ ys){
  __shared__ float sAn[N_];
  __shared__ float sA[N_][4];
  __shared__ float sB[N_][4];
  int tid = threadIdx.x, lane = tid & 63, w = tid >> 6;
  int ch = blockIdx.x;
  int b = ch >> 9, d = ch & (DR_ - 1);
  if (tid < N_) sAn[tid] = -fminf(__expf(alog[d * N_ + tid]), 10000.f);
  long col = (long)b * R_ + tid;
  float dl = deltaT[(long)d * REGS + col];
  float uu = uT[(long)d * REGS + col];
  float zz = zT[(long)d * REGS + col];
  float Dd = Dp[d];
  float part = 0.f;
  __syncthreads();
  for (int nc = 0; nc < 6; ++nc){
    float bmv[8], cmv[8];
#pragma unroll
    for (int j = 0; j < 8; ++j){
      bmv[j] = BmT[(long)(nc * 8 + j) * REGS + col];
      cmv[j] = CmT[(long)(nc * 8 + j) * REGS + col];
    }
    float aA[8], aB[8];
#pragma unroll
    for (int j = 0; j < 8; ++j){
      int n = nc * 8 + j;
      float cc = fminf(fmaxf(dl * sAn[n], -30.f), 30.f);
      float a = exp2f(cc * 1.44269504f);
      float bv = dl * bmv[j] * uu;
#pragma unroll
      for (int s = 1; s < 64; s <<= 1){
        float a_sh = __shfl_up(a, (unsigned)s, 64);
        float b_sh = __shfl_up(bv, (unsigned)s, 64);
        float nb = fmaf(a, b_sh, bv);
        float na = a * a_sh;
        if (lane >= s){ bv = nb; a = na; }
      }
      aA[j] = a; aB[j] = bv;
      if (lane == 63){ sA[n][w] = a; sB[n][w] = bv; }
    }
    __syncthreads();
#pragma unroll
    for (int j = 0; j < 8; ++j){
      int n = nc * 8 + j;
      float hin = 0.f;
#pragma unroll
      for (int tt = 0; tt < 3; ++tt){
        if (tt < w) hin = sA[n][tt] * hin + sB[n][tt];
      }
      float h = fmaf(aA[j], hin, aB[j]);
      part = fmaf(cmv[j], h, part);
    }
    if (nc < 5) __syncthreads();
  }
  float yv = part + Dd * uu;
  float sz = zz / (1.f + __expf(-zz));
  ys[col * DR_ + d] = yv * sz;
}

// ---------------- R6: out_proj + residual + final LN + l2norm, 4 rows ------
__global__ __launch_bounds__(512) void k_out(
    const float* __restrict__ ys, const float* __restrict__ W,
    const float* __restrict__ region, const float* __restrict__ lnw,
    const float* __restrict__ lnb, float* __restrict__ outp,
    float* __restrict__ rt){
  __shared__ __align__(16) float yr[4][DR_];
  __shared__ float red[40];
  int tid = threadIdx.x;
  int r0 = blockIdx.x * 4;
  for (int i = tid; i < 4 * DR_; i += 512) yr[i >> 9][i & 511] = ys[(long)r0 * DR_ + i];
  __syncthreads();
  float y[4] = {0,0,0,0};
  for (int k0 = 0; k0 < DR_; k0 += 8){
    float wv[8];
#pragma unroll
    for (int j = 0; j < 8; ++j) wv[j] = W[(k0 + j) * DR_ + tid];
#pragma unroll
    for (int j4 = 0; j4 < 8; j4 += 4){
#pragma unroll
      for (int i = 0; i < 4; ++i){
        float4 x = *(const float4*)(&yr[i][k0 + j4]);
        y[i] = fmaf(x.x, wv[j4], y[i]);
        y[i] = fmaf(x.y, wv[j4 + 1], y[i]);
        y[i] = fmaf(x.z, wv[j4 + 2], y[i]);
        y[i] = fmaf(x.w, wv[j4 + 3], y[i]);
      }
    }
  }
  float v[4], t4[4];
#pragma unroll
  for (int i = 0; i < 4; ++i){
    if (isnan(y[i])) y[i] = 0.f; else if (isinf(y[i])) y[i] = (y[i] > 0.f) ? 1.f : -1.f;
    v[i] = region[(long)(r0 + i) * DR_ + tid] + y[i];
    t4[i] = v[i];
  }
  block_sum4(t4, red);
  float dv[4];
#pragma unroll
  for (int i = 0; i < 4; ++i){ dv[i] = v[i] - t4[i] * (1.f / DR_); t4[i] = dv[i] * dv[i]; }
  block_sum4(t4, red);
  float o[4];
  float lw = lnw[tid], lb = lnb[tid];
#pragma unroll
  for (int i = 0; i < 4; ++i){
    o[i] = dv[i] * rsqrtf(t4[i] * (1.f / DR_) + 1e-5f) * lw + lb;
    outp[(long)(r0 + i) * DR_ + tid] = o[i];
    t4[i] = o[i] * o[i];
  }
  block_sum4(t4, red);
#pragma unroll
  for (int i = 0; i < 4; ++i)
    rt[(long)(r0 + i) * DR_ + tid] = o[i] / fmaxf(sqrtf(t4[i]), 1e-6f);
}

// ---------------- R7: similarity losses, 4 query rows per block ------------
__global__ __launch_bounds__(512) void k_loss(
    const float* __restrict__ rt, const int* __restrict__ nearm,
    const int* __restrict__ farm, float* __restrict__ accum){
  __shared__ __align__(16) float ar[4][DR_];
  __shared__ float ps[2][4][256];
  __shared__ float wsum[8][4];
  int blk = blockIdx.x, tid = threadIdx.x;
  int b = blk >> 6, q0 = (blk & 63) * 4;
  const float* rtb = rt + (long)b * R_ * DR_;
  for (int i = tid; i < 4 * DR_; i += 512) ar[i >> 9][i & 511] = rtb[(long)q0 * DR_ + i];
  __syncthreads();
  int s = tid & 255, h = tid >> 8;
  const float* rsrow = rtb + (long)s * DR_ + h * 256;
  float dq[4] = {0.f, 0.f, 0.f, 0.f};
  for (int k = 0; k < 256; k += 4){
    float4 yv = *(const float4*)(rsrow + k);
#pragma unroll
    for (int q = 0; q < 4; ++q){
      float4 x = *(const float4*)(&ar[q][h * 256 + k]);
      dq[q] += x.x * yv.x + x.y * yv.y + x.z * yv.z + x.w * yv.w;
    }
  }
#pragma unroll
  for (int q = 0; q < 4; ++q) ps[h][q][s] = dq[q];
  __syncthreads();
  float nl = 0.f, fl = 0.f, nc = 0.f, fc = 0.f;
  if (tid < 256){
#pragma unroll
    for (int q = 0; q < 4; ++q){
      float dot = ps[0][q][tid] + ps[1][q][tid];
      int nm = nearm[(q0 + q) * R_ + tid], fm = farm[(q0 + q) * R_ + tid];
      if (nm){ nl += 1.f - dot; if (b == 0) nc += 1.f; }
      if (fm){ fl += fmaxf(dot - 0.2f, 0.f); if (b == 0) fc += 1.f; }
    }
  }
  nl = wred_sum(nl); fl = wred_sum(fl); nc = wred_sum(nc); fc = wred_sum(fc);
  int w = tid >> 6, lane = tid & 63;
  if (lane == 0){ wsum[w][0] = nl; wsum[w][1] = fl; wsum[w][2] = nc; wsum[w][3] = fc; }
  __syncthreads();
  if (tid == 0){
    float a0 = 0, a1 = 0, a2 = 0, a3 = 0;
    for (int i = 0; i < 8; i++){ a0 += wsum[i][0]; a1 += wsum[i][1]; a2 += wsum[i][2]; a3 += wsum[i][3]; }
    atomicAdd(&accum[0], a0); atomicAdd(&accum[1], a1);
    if (b == 0){ atomicAdd(&accum[2], a2); atomicAdd(&accum[3], a3); }
  }
}

__global__ void k_final(const float* __restrict__ accum, float* __restrict__ outp){
  if (threadIdx.x == 0){
    float loss = accum[0] / fmaxf(accum[2], 1.f) + accum[1] / fmaxf(accum[3], 1.f);
    outp[REGS * DR_] = loss;
  }
}

extern "C" void kernel_launch(void* const* d_in, const int* in_sizes, int n_in,
                              void* d_out, int out_size, void* d_ws, size_t ws_size,
                              hipStream_t stream){
  const float* pt    = (const float*)d_in[0];
  const int*   pmask = (const int*)d_in[1];
  const int*   nearm = (const int*)d_in[2];
  const int*   farm  = (const int*)d_in[3];
  const float* lp    = (const float*)d_in[4];
  const float* glnw  = (const float*)d_in[5];
  const float* glnb  = (const float*)d_in[6];
  const float* gw1   = (const float*)d_in[7];
  const float* gb1   = (const float*)d_in[8];
  const float* gw2   = (const float*)d_in[9];
  const float* pln1w = (const float*)d_in[11];
  const float* pln1b = (const float*)d_in[12];
  const float* pw1   = (const float*)d_in[13];
  const float* pb1   = (const float*)d_in[14];
  const float* pw2   = (const float*)d_in[15];
  const float* pb2   = (const float*)d_in[16];
  const float* pln2w = (const float*)d_in[17];
  const float* pln2b = (const float*)d_in[18];
  const float* inpw  = (const float*)d_in[19];
  const float* xpw   = (const float*)d_in[20];
  const float* dtw   = (const float*)d_in[21];
  const float* dtb   = (const float*)d_in[22];
  const float* alog  = (const float*)d_in[23];
  const float* dpar  = (const float*)d_in[24];
  const float* opw   = (const float*)d_in[25];
  const float* slnw  = (const float*)d_in[26];
  const float* slnb  = (const float*)d_in[27];

  char* ws = (char*)d_ws;
  size_t off = 0;
  auto alloc = [&](size_t bytes){ size_t o = off; off += (bytes + 255) & ~(size_t)255; return o; };
  ushort_t* W1pT  = (ushort_t*)(ws + alloc((size_t)DR_ * DP_ * 2));
  float* s1     = (float*)(ws + alloc(DR_ * 4));
  float* b1p    = (float*)(ws + alloc(DR_ * 4));
  ushort_t* wblob = (ushort_t*)(ws + alloc((size_t)NW_TOT * 2));
  ushort_t* xb  = (ushort_t*)(ws + alloc((size_t)MROWS * DP_ * 2));
  float* mu     = (float*)(ws + alloc((size_t)MROWS * 4));
  float* rsg    = (float*)(ws + alloc((size_t)MROWS * 4));
  float* pooled = (float*)(ws + alloc((size_t)REGS * DP_ * 4));
  float* region = (float*)(ws + alloc((size_t)REGS * DR_ * 4));
  float* uT     = (float*)(ws + alloc((size_t)REGS * DR_ * 4));
  float* zT     = (float*)(ws + alloc((size_t)REGS * DR_ * 4));
  float* deltaT = (float*)(ws + alloc((size_t)REGS * DR_ * 4));
  float* BmT    = (float*)(ws + alloc((size_t)REGS * N_ * 4));
  float* CmT    = (float*)(ws + alloc((size_t)REGS * N_ * 4));
  float* ys     = (float*)(ws + alloc((size_t)REGS * DR_ * 4));
  float* rt     = (float*)(ws + alloc((size_t)REGS * DR_ * 4));
  float* accum  = (float*)(ws + alloc(4 * 4));

  float* outp = (float*)d_out;

  k_prep<<<dim3(8), dim3(512), 0, stream>>>(gw1, glnw, glnb, gb1, W1pT, s1, b1p, accum);
  k_cast<<<dim3((NW_TOT / 4 + 511) / 512), dim3(512), 0, stream>>>(pw1, pw2, inpw, xpw, dtw, wblob);
  k_xform<<<dim3(MROWS / 8), dim3(512), 0, stream>>>(pt, lp, xb, mu, rsg);
  k_gate_pool<<<dim3(MROWS / 128), dim3(1024), 0, stream>>>(xb, W1pT, mu, rsg, s1, b1p, gw2, pmask, pooled);
  k_region<<<dim3(REGS / 2), dim3(512), 0, stream>>>(pooled, pln1w, pln1b, wblob, pb1, pb2, pln2w, pln2b,
                                                     dtb, region, uT, zT, deltaT, BmT, CmT);
  k_scan<<<dim3(B_ * DR_), dim3(256), 0, stream>>>(deltaT, uT, zT, BmT, CmT, alog, dpar, ys);
  k_out<<<dim3(REGS / 4), dim3(512), 0, stream>>>(ys, opw, region, slnw, slnb, outp, rt);
  k_loss<<<dim3(REGS / 4), dim3(512), 0, stream>>>(rt, nearm, farm, accum);
  k_final<<<dim3(1), dim3(64), 0, stream>>>(accum, outp);
}